// Round 3
// baseline (200.270 us; speedup 1.0000x reference)
//
#include <hip/hip_runtime.h>

typedef unsigned short u16;
typedef _Float16 f16;

using half8   = __attribute__((ext_vector_type(8))) _Float16;
using f32x4   = __attribute__((ext_vector_type(4))) float;
using ushort8 = __attribute__((ext_vector_type(8))) unsigned short;
using us4     = __attribute__((ext_vector_type(4))) unsigned short;
using float4v = __attribute__((ext_vector_type(4))) float;

#define B_  8
#define S_  2048
#define D_  512

__device__ __forceinline__ u16 f2h(float f) {
  f16 h = (f16)f;
  u16 u;
  __builtin_memcpy(&u, &h, 2);
  return u;
}

__device__ __forceinline__ float h2f(u16 h) {
  f16 x;
  __builtin_memcpy(&x, &h, 2);
  return (float)x;
}

__device__ __forceinline__ void stage16(const void* g, void* l) {
  __builtin_amdgcn_global_load_lds((const __attribute__((address_space(1))) void*)g,
                                   (__attribute__((address_space(3))) void*)l,
                                   16, 0, 0);
}

// C[M x N] = A[M x K] * B[N x K]^T, fp16 inputs, fp32 accum.
// 128x128 tile, BK=32, 256 threads = 4 waves in 2x2, each wave 64x64 (4x4 frags).
// mfma_f32_16x16x32_f16: A/B frag: row/col = lane&15, k = (lane>>4)*8 + j
//                        C/D frag: col = lane&15, row = (lane>>4)*4 + reg
__device__ __forceinline__ void gemm_core(const u16* __restrict__ A, const u16* __restrict__ B,
                                          int K, int m0, int n0,
                                          u16* ldsA, u16* ldsB, f32x4 acc[4][4]) {
  const int tid  = threadIdx.x;
  const int lane = tid & 63;
  const int wave = tid >> 6;
  const int wr = wave >> 1, wc = wave & 1;
  const int srow = lane >> 2;        // staging row within 16-row chunk
  const int scol = (lane & 3) * 8;   // staging k offset (elements)
  const int fr = lane & 15;
  const int fk = (lane >> 4) * 8;

  const f32x4 vzero = {0.f, 0.f, 0.f, 0.f};
  #pragma unroll
  for (int m = 0; m < 4; ++m)
    #pragma unroll
    for (int n = 0; n < 4; ++n)
      acc[m][n] = vzero;

  for (int k0 = 0; k0 < K; k0 += 32) {
    // stage A[128][32] and B[128][32] fp16 tiles; wave w covers rows [w*32, w*32+32)
    const u16* gA = A + (size_t)(m0 + wave * 32 + srow) * K + k0 + scol;
    stage16(gA,                 ldsA + (wave * 32) * 32);
    stage16(gA + (size_t)16 * K, ldsA + (wave * 32 + 16) * 32);
    const u16* gB = B + (size_t)(n0 + wave * 32 + srow) * K + k0 + scol;
    stage16(gB,                 ldsB + (wave * 32) * 32);
    stage16(gB + (size_t)16 * K, ldsB + (wave * 32 + 16) * 32);
    __syncthreads();

    half8 a[4], b[4];
    #pragma unroll
    for (int m = 0; m < 4; ++m)
      a[m] = *(const half8*)(ldsA + (wr * 64 + m * 16 + fr) * 32 + fk);
    #pragma unroll
    for (int n = 0; n < 4; ++n)
      b[n] = *(const half8*)(ldsB + (wc * 64 + n * 16 + fr) * 32 + fk);
    #pragma unroll
    for (int m = 0; m < 4; ++m)
      #pragma unroll
      for (int n = 0; n < 4; ++n)
        acc[m][n] = __builtin_amdgcn_mfma_f32_16x16x32_f16(a[m], b[n], acc[m][n], 0, 0, 0);
    __syncthreads();
  }
}

// ---------------- projections: Q/K normal fp16 store, V transposed [b][d][s] ----------------
__global__ __launch_bounds__(256) void proj_kernel(
    const u16* __restrict__ xh, const u16* __restrict__ Wh,
    const float* __restrict__ bq, const float* __restrict__ bk, const float* __restrict__ bv,
    u16* __restrict__ Qb, u16* __restrict__ Kb, u16* __restrict__ Vt) {
  __shared__ __align__(16) u16 ldsA[128 * 32];
  __shared__ __align__(16) u16 ldsB[128 * 32];
  const int z  = blockIdx.z;
  const int m0 = blockIdx.y * 128;
  const int n0 = blockIdx.x * 128;
  const u16* W = Wh + (size_t)z * D_ * D_;
  const float* bias = (z == 0) ? bq : (z == 1) ? bk : bv;
  f32x4 acc[4][4];
  gemm_core(xh, W, D_, m0, n0, ldsA, ldsB, acc);

  const int lane = threadIdx.x & 63;
  const int wave = threadIdx.x >> 6;
  const int wr = wave >> 1, wc = wave & 1;
  #pragma unroll
  for (int m = 0; m < 4; ++m) {
    const int gr0 = m0 + wr * 64 + m * 16 + ((lane >> 4) << 2);
    #pragma unroll
    for (int n = 0; n < 4; ++n) {
      const int gc = n0 + wc * 64 + n * 16 + (lane & 15);
      const float bb = bias[gc];
      if (z < 2) {
        u16* O = z ? Kb : Qb;
        #pragma unroll
        for (int r = 0; r < 4; ++r)
          O[(size_t)(gr0 + r) * D_ + gc] = f2h(acc[m][n][r] + bb);
      } else {
        const int bidx = gr0 >> 11;      // batch (2048 rows per batch; tiles never straddle)
        const int s    = gr0 & 2047;
        us4 p;
        #pragma unroll
        for (int r = 0; r < 4; ++r) p[r] = f2h(acc[m][n][r] + bb);
        *(us4*)(Vt + ((size_t)bidx * D_ + gc) * S_ + s) = p;
      }
    }
  }
}

// ---------------- QK^T -> E fp16 ----------------
__global__ __launch_bounds__(256) void qk_kernel(
    const u16* __restrict__ Qb, const u16* __restrict__ Kb, u16* __restrict__ E,
    size_t sA, size_t sE) {
  __shared__ __align__(16) u16 ldsA[128 * 32];
  __shared__ __align__(16) u16 ldsB[128 * 32];
  const int z  = blockIdx.z;
  const int m0 = blockIdx.y * 128;
  const int n0 = blockIdx.x * 128;
  f32x4 acc[4][4];
  gemm_core(Qb + (size_t)z * sA, Kb + (size_t)z * sA, D_, m0, n0, ldsA, ldsB, acc);

  u16* Eb = E + (size_t)z * sE;
  const int lane = threadIdx.x & 63;
  const int wave = threadIdx.x >> 6;
  const int wr = wave >> 1, wc = wave & 1;
  #pragma unroll
  for (int m = 0; m < 4; ++m) {
    const int gr0 = m0 + wr * 64 + m * 16 + ((lane >> 4) << 2);
    #pragma unroll
    for (int n = 0; n < 4; ++n) {
      const int gc = n0 + wc * 64 + n * 16 + (lane & 15);
      #pragma unroll
      for (int r = 0; r < 4; ++r)
        Eb[(size_t)(gr0 + r) * S_ + gc] = f2h(acc[m][n][r]);
    }
  }
}

// ---------------- row softmax, in place fp16 -> fp16 ----------------
__global__ __launch_bounds__(256) void softmax_kernel(u16* __restrict__ E) {
  const int row  = blockIdx.x * 4 + (threadIdx.x >> 6);
  const int lane = threadIdx.x & 63;
  u16* R = E + (size_t)row * S_;
  float e[32];
  #pragma unroll
  for (int i = 0; i < 4; ++i) {
    ushort8 v = *(const ushort8*)(R + i * 512 + lane * 8);
    #pragma unroll
    for (int j = 0; j < 8; ++j) e[i * 8 + j] = h2f(v[j]);
  }
  float m = e[0];
  #pragma unroll
  for (int i = 1; i < 32; ++i) m = fmaxf(m, e[i]);
  for (int off = 32; off > 0; off >>= 1) m = fmaxf(m, __shfl_xor(m, off, 64));
  float s = 0.f;
  #pragma unroll
  for (int i = 0; i < 32; ++i) { e[i] = __expf(e[i] - m); s += e[i]; }
  for (int off = 32; off > 0; off >>= 1) s += __shfl_xor(s, off, 64);
  const float inv = 1.f / s;
  #pragma unroll
  for (int i = 0; i < 4; ++i) {
    ushort8 v;
    #pragma unroll
    for (int j = 0; j < 8; ++j) v[j] = f2h(e[i * 8 + j] * inv);
    *(ushort8*)(R + i * 512 + lane * 8) = v;
  }
}

// ---------------- PV -> fp32 out ----------------
__global__ __launch_bounds__(256) void pv_kernel(
    const u16* __restrict__ P, const u16* __restrict__ Vt, float* __restrict__ out,
    size_t sP, size_t sV, size_t sO) {
  __shared__ __align__(16) u16 ldsA[128 * 32];
  __shared__ __align__(16) u16 ldsB[128 * 32];
  const int z  = blockIdx.z;
  const int m0 = blockIdx.y * 128;
  const int n0 = blockIdx.x * 128;
  f32x4 acc[4][4];
  gemm_core(P + (size_t)z * sP, Vt + (size_t)z * sV, S_, m0, n0, ldsA, ldsB, acc);

  float* Ob = out + (size_t)z * sO;
  const int lane = threadIdx.x & 63;
  const int wave = threadIdx.x >> 6;
  const int wr = wave >> 1, wc = wave & 1;
  #pragma unroll
  for (int m = 0; m < 4; ++m) {
    const int gr0 = m0 + wr * 64 + m * 16 + ((lane >> 4) << 2);
    #pragma unroll
    for (int n = 0; n < 4; ++n) {
      const int gc = n0 + wc * 64 + n * 16 + (lane & 15);
      #pragma unroll
      for (int r = 0; r < 4; ++r)
        Ob[(size_t)(gr0 + r) * D_ + gc] = acc[m][n][r];
    }
  }
}

// ---------------- fp32 -> fp16 convert ----------------
__global__ __launch_bounds__(256) void cvt_kernel(const float* __restrict__ in,
                                                  u16* __restrict__ out, int n8) {
  const int i = blockIdx.x * 256 + threadIdx.x;
  if (i >= n8) return;
  const float4v a = *(const float4v*)(in + (size_t)i * 8);
  const float4v b = *(const float4v*)(in + (size_t)i * 8 + 4);
  ushort8 o;
  o[0] = f2h(a[0]); o[1] = f2h(a[1]); o[2] = f2h(a[2]); o[3] = f2h(a[3]);
  o[4] = f2h(b[0]); o[5] = f2h(b[1]); o[6] = f2h(b[2]); o[7] = f2h(b[3]);
  *(ushort8*)(out + (size_t)i * 8) = o;
}

extern "C" void kernel_launch(void* const* d_in, const int* in_sizes, int n_in,
                              void* d_out, int out_size, void* d_ws, size_t ws_size,
                              hipStream_t stream) {
  (void)in_sizes; (void)n_in; (void)out_size;
  const float* x  = (const float*)d_in[0];
  const float* Wq = (const float*)d_in[1];
  const float* bq = (const float*)d_in[2];
  const float* Wk = (const float*)d_in[3];
  const float* bk = (const float*)d_in[4];
  const float* Wv = (const float*)d_in[5];
  const float* bv = (const float*)d_in[6];
  float* out = (float*)d_out;

  char* ws = (char*)d_ws;
  size_t off = 0;
  auto alloc = [&](size_t bytes) -> char* {
    char* p = ws + off;
    off += (bytes + 255) & ~(size_t)255;
    return p;
  };
  const size_t MS = (size_t)B_ * S_;  // 16384 rows total
  u16* xh = (u16*)alloc(MS * D_ * 2);
  u16* Wh = (u16*)alloc(3ull * D_ * D_ * 2);
  u16* Qb = (u16*)alloc(MS * D_ * 2);
  u16* Kb = (u16*)alloc(MS * D_ * 2);
  u16* Vt = (u16*)alloc(MS * D_ * 2);
  const size_t Efull = (size_t)B_ * S_ * S_ * 2;
  const bool full = ws_size >= off + Efull;  // ~136 MB total; else per-batch E (~77 MB)
  u16* E = (u16*)alloc(full ? Efull : (size_t)S_ * S_ * 2);

  // fp32 -> fp16 converts
  {
    const int n8 = (int)(MS * D_ / 8);
    cvt_kernel<<<dim3((n8 + 255) / 256), dim3(256), 0, stream>>>(x, xh, n8);
    const int w8 = D_ * D_ / 8;
    cvt_kernel<<<dim3((w8 + 255) / 256), dim3(256), 0, stream>>>(Wq, Wh, w8);
    cvt_kernel<<<dim3((w8 + 255) / 256), dim3(256), 0, stream>>>(Wk, Wh + D_ * D_, w8);
    cvt_kernel<<<dim3((w8 + 255) / 256), dim3(256), 0, stream>>>(Wv, Wh + 2 * D_ * D_, w8);
  }

  // Q/K/V projections (z = 0/1/2)
  proj_kernel<<<dim3(D_ / 128, MS / 128, 3), dim3(256), 0, stream>>>(
      xh, Wh, bq, bk, bv, Qb, Kb, Vt);

  if (full) {
    qk_kernel<<<dim3(S_ / 128, S_ / 128, B_), dim3(256), 0, stream>>>(
        Qb, Kb, E, (size_t)S_ * D_, (size_t)S_ * S_);
    softmax_kernel<<<dim3(B_ * S_ / 4), dim3(256), 0, stream>>>(E);
    pv_kernel<<<dim3(D_ / 128, S_ / 128, B_), dim3(256), 0, stream>>>(
        E, Vt, out, (size_t)S_ * S_, (size_t)D_ * S_, (size_t)S_ * D_);
  } else {
    for (int b = 0; b < B_; ++b) {
      qk_kernel<<<dim3(S_ / 128, S_ / 128, 1), dim3(256), 0, stream>>>(
          Qb + (size_t)b * S_ * D_, Kb + (size_t)b * S_ * D_, E, 0, 0);
      softmax_kernel<<<dim3(S_ / 4), dim3(256), 0, stream>>>(E);
      pv_kernel<<<dim3(D_ / 128, S_ / 128, 1), dim3(256), 0, stream>>>(
          E, Vt + (size_t)b * D_ * S_, out + (size_t)b * S_ * D_, 0, 0, 0);
    }
  }
}

// Round 4
// 170.088 us; speedup vs baseline: 1.1775x; 1.1775x over previous
//
#include <hip/hip_runtime.h>

typedef unsigned short u16;
typedef _Float16 f16;

using half8   = __attribute__((ext_vector_type(8))) _Float16;
using f32x4   = __attribute__((ext_vector_type(4))) float;
using ushort8 = __attribute__((ext_vector_type(8))) unsigned short;
using us4     = __attribute__((ext_vector_type(4))) unsigned short;
using float4v = __attribute__((ext_vector_type(4))) float;

#define B_  8
#define S_  2048
#define D_  512
#define BK  64

__device__ __forceinline__ u16 f2h(float f) {
  f16 h = (f16)f;
  u16 u;
  __builtin_memcpy(&u, &h, 2);
  return u;
}

__device__ __forceinline__ float h2f(u16 h) {
  f16 x;
  __builtin_memcpy(&x, &h, 2);
  return (float)x;
}

__device__ __forceinline__ void stage16(const void* g, void* l) {
  __builtin_amdgcn_global_load_lds((const __attribute__((address_space(1))) void*)g,
                                   (__attribute__((address_space(3))) void*)l,
                                   16, 0, 0);
}

// XCD-aware bijective remap: contiguous chunk of linear ids per XCD.
// All GEMM grids have nwg % 8 == 0.
__device__ __forceinline__ void xcd_remap(int& bx, int& by, int& bz) {
  const int lin = ((int)blockIdx.z * (int)gridDim.y + (int)blockIdx.y) * (int)gridDim.x
                  + (int)blockIdx.x;
  const int nwg = (int)gridDim.x * (int)gridDim.y * (int)gridDim.z;
  const int swz = (lin & 7) * (nwg >> 3) + (lin >> 3);
  bx = swz % (int)gridDim.x;
  const int tmp = swz / (int)gridDim.x;
  by = tmp % (int)gridDim.y;
  bz = tmp / (int)gridDim.y;
}

// C[M x N] = A[M x K] * B[N x K]^T, fp16 inputs, fp32 accum.
// 128x128 tile, BK=64, double-buffered LDS (stage t+1 before compute t, one
// barrier per iter). LDS layout XOR-swizzled: logical (row, col8) lives at
// elem row*64 + 8*(col8 ^ (row&7)); achieved by pre-swizzling the GLOBAL
// source column in the linear global_load_lds write (rule #21 both-sides).
// mfma_f32_16x16x32_f16 frags: A/B row/col = lane&15, k = (lane>>4)*8 + j
//                              C/D col = lane&15, row = (lane>>4)*4 + reg
__device__ __forceinline__ void gemm_core(const u16* __restrict__ A, const u16* __restrict__ B,
                                          int K, int m0, int n0,
                                          u16* ldsA, u16* ldsB, f32x4 acc[4][4]) {
  const int tid  = threadIdx.x;
  const int lane = tid & 63;
  const int wave = tid >> 6;
  const int wr = wave >> 1, wc = wave & 1;
  // staging: sweep s covers rows [s*32, s*32+32); wave covers 8 rows; lane -> 16B
  const int srow = wave * 8 + (lane >> 3);
  const int scol = (((lane & 7) ^ (lane >> 3)) << 3);  // pre-swizzled global col (elems)
  const int fr   = lane & 15;
  const int fgrp = lane >> 4;  // 0..3

  const f32x4 vzero = {0.f, 0.f, 0.f, 0.f};
  #pragma unroll
  for (int m = 0; m < 4; ++m)
    #pragma unroll
    for (int n = 0; n < 4; ++n)
      acc[m][n] = vzero;

  const int T = K / BK;
  const u16* gA = A + (size_t)(m0 + srow) * K + scol;
  const u16* gB = B + (size_t)(n0 + srow) * K + scol;

  int cur = 0;
  // prologue: stage tile 0 into buffer 0
  #pragma unroll
  for (int s = 0; s < 4; ++s) {
    stage16(gA + (size_t)s * 32 * K, ldsA + (s * 32 + wave * 8) * BK);
    stage16(gB + (size_t)s * 32 * K, ldsB + (s * 32 + wave * 8) * BK);
  }
  __syncthreads();

  for (int t = 0; t < T; ++t) {
    if (t + 1 < T) {  // issue next-tile loads before compute (overlap under MFMA)
      const u16* pa = gA + (size_t)(t + 1) * BK;
      const u16* pb = gB + (size_t)(t + 1) * BK;
      u16* la = ldsA + (cur ^ 1) * (128 * BK);
      u16* lb = ldsB + (cur ^ 1) * (128 * BK);
      #pragma unroll
      for (int s = 0; s < 4; ++s) {
        stage16(pa + (size_t)s * 32 * K, la + (s * 32 + wave * 8) * BK);
        stage16(pb + (size_t)s * 32 * K, lb + (s * 32 + wave * 8) * BK);
      }
    }
    const u16* la = ldsA + cur * (128 * BK);
    const u16* lb = ldsB + cur * (128 * BK);
    #pragma unroll
    for (int kk = 0; kk < 2; ++kk) {
      const int ce = ((((kk << 2) | fgrp) ^ (fr & 7)) << 3);  // swizzled col (elems)
      half8 a[4], b[4];
      #pragma unroll
      for (int m = 0; m < 4; ++m)
        a[m] = *(const half8*)(la + (wr * 64 + m * 16 + fr) * BK + ce);
      #pragma unroll
      for (int n = 0; n < 4; ++n)
        b[n] = *(const half8*)(lb + (wc * 64 + n * 16 + fr) * BK + ce);
      #pragma unroll
      for (int m = 0; m < 4; ++m)
        #pragma unroll
        for (int n = 0; n < 4; ++n)
          acc[m][n] = __builtin_amdgcn_mfma_f32_16x16x32_f16(a[m], b[n], acc[m][n], 0, 0, 0);
    }
    __syncthreads();  // drains vmcnt (stage done) + lgkmcnt; one barrier per iter
    cur ^= 1;
  }
}

// ---------------- projections: Q/K normal fp16 store, V transposed [b][d][s] ----------------
__global__ __launch_bounds__(256) void proj_kernel(
    const u16* __restrict__ xh, const u16* __restrict__ Wh,
    const float* __restrict__ bq, const float* __restrict__ bk, const float* __restrict__ bv,
    u16* __restrict__ Qb, u16* __restrict__ Kb, u16* __restrict__ Vt) {
  __shared__ __align__(16) u16 ldsA[2 * 128 * BK];
  __shared__ __align__(16) u16 ldsB[2 * 128 * BK];
  int bx, by, bz;
  xcd_remap(bx, by, bz);
  const int z  = bz;
  const int m0 = by * 128;
  const int n0 = bx * 128;
  const u16* W = Wh + (size_t)z * D_ * D_;
  const float* bias = (z == 0) ? bq : (z == 1) ? bk : bv;
  f32x4 acc[4][4];
  gemm_core(xh, W, D_, m0, n0, ldsA, ldsB, acc);

  const int lane = threadIdx.x & 63;
  const int wave = threadIdx.x >> 6;
  const int wr = wave >> 1, wc = wave & 1;
  #pragma unroll
  for (int m = 0; m < 4; ++m) {
    const int gr0 = m0 + wr * 64 + m * 16 + ((lane >> 4) << 2);
    #pragma unroll
    for (int n = 0; n < 4; ++n) {
      const int gc = n0 + wc * 64 + n * 16 + (lane & 15);
      const float bb = bias[gc];
      if (z < 2) {
        u16* O = z ? Kb : Qb;
        #pragma unroll
        for (int r = 0; r < 4; ++r)
          O[(size_t)(gr0 + r) * D_ + gc] = f2h(acc[m][n][r] + bb);
      } else {
        const int bidx = gr0 >> 11;      // batch (2048 rows per batch; tiles never straddle)
        const int s    = gr0 & 2047;
        us4 p;
        #pragma unroll
        for (int r = 0; r < 4; ++r) p[r] = f2h(acc[m][n][r] + bb);
        *(us4*)(Vt + ((size_t)bidx * D_ + gc) * S_ + s) = p;
      }
    }
  }
}

// ---------------- QK^T -> E fp16 ----------------
__global__ __launch_bounds__(256) void qk_kernel(
    const u16* __restrict__ Qb, const u16* __restrict__ Kb, u16* __restrict__ E,
    size_t sA, size_t sE) {
  __shared__ __align__(16) u16 ldsA[2 * 128 * BK];
  __shared__ __align__(16) u16 ldsB[2 * 128 * BK];
  int bx, by, bz;
  xcd_remap(bx, by, bz);
  const int z  = bz;
  const int m0 = by * 128;
  const int n0 = bx * 128;
  f32x4 acc[4][4];
  gemm_core(Qb + (size_t)z * sA, Kb + (size_t)z * sA, D_, m0, n0, ldsA, ldsB, acc);

  u16* Eb = E + (size_t)z * sE;
  const int lane = threadIdx.x & 63;
  const int wave = threadIdx.x >> 6;
  const int wr = wave >> 1, wc = wave & 1;
  #pragma unroll
  for (int m = 0; m < 4; ++m) {
    const int gr0 = m0 + wr * 64 + m * 16 + ((lane >> 4) << 2);
    #pragma unroll
    for (int n = 0; n < 4; ++n) {
      const int gc = n0 + wc * 64 + n * 16 + (lane & 15);
      #pragma unroll
      for (int r = 0; r < 4; ++r)
        Eb[(size_t)(gr0 + r) * S_ + gc] = f2h(acc[m][n][r]);
    }
  }
}

// ---------------- row softmax, in place fp16 -> fp16 ----------------
__global__ __launch_bounds__(256) void softmax_kernel(u16* __restrict__ E) {
  const int row  = blockIdx.x * 4 + (threadIdx.x >> 6);
  const int lane = threadIdx.x & 63;
  u16* R = E + (size_t)row * S_;
  float e[32];
  #pragma unroll
  for (int i = 0; i < 4; ++i) {
    ushort8 v = *(const ushort8*)(R + i * 512 + lane * 8);
    #pragma unroll
    for (int j = 0; j < 8; ++j) e[i * 8 + j] = h2f(v[j]);
  }
  float m = e[0];
  #pragma unroll
  for (int i = 1; i < 32; ++i) m = fmaxf(m, e[i]);
  for (int off = 32; off > 0; off >>= 1) m = fmaxf(m, __shfl_xor(m, off, 64));
  float s = 0.f;
  #pragma unroll
  for (int i = 0; i < 32; ++i) { e[i] = __expf(e[i] - m); s += e[i]; }
  for (int off = 32; off > 0; off >>= 1) s += __shfl_xor(s, off, 64);
  const float inv = 1.f / s;
  #pragma unroll
  for (int i = 0; i < 4; ++i) {
    ushort8 v;
    #pragma unroll
    for (int j = 0; j < 8; ++j) v[j] = f2h(e[i * 8 + j] * inv);
    *(ushort8*)(R + i * 512 + lane * 8) = v;
  }
}

// ---------------- PV -> fp32 out ----------------
__global__ __launch_bounds__(256) void pv_kernel(
    const u16* __restrict__ P, const u16* __restrict__ Vt, float* __restrict__ out,
    size_t sP, size_t sV, size_t sO) {
  __shared__ __align__(16) u16 ldsA[2 * 128 * BK];
  __shared__ __align__(16) u16 ldsB[2 * 128 * BK];
  int bx, by, bz;
  xcd_remap(bx, by, bz);
  const int z  = bz;
  const int m0 = by * 128;
  const int n0 = bx * 128;
  f32x4 acc[4][4];
  gemm_core(P + (size_t)z * sP, Vt + (size_t)z * sV, S_, m0, n0, ldsA, ldsB, acc);

  float* Ob = out + (size_t)z * sO;
  const int lane = threadIdx.x & 63;
  const int wave = threadIdx.x >> 6;
  const int wr = wave >> 1, wc = wave & 1;
  #pragma unroll
  for (int m = 0; m < 4; ++m) {
    const int gr0 = m0 + wr * 64 + m * 16 + ((lane >> 4) << 2);
    #pragma unroll
    for (int n = 0; n < 4; ++n) {
      const int gc = n0 + wc * 64 + n * 16 + (lane & 15);
      #pragma unroll
      for (int r = 0; r < 4; ++r)
        Ob[(size_t)(gr0 + r) * D_ + gc] = acc[m][n][r];
    }
  }
}

// ---------------- fp32 -> fp16 convert ----------------
__global__ __launch_bounds__(256) void cvt_kernel(const float* __restrict__ in,
                                                  u16* __restrict__ out, int n8) {
  const int i = blockIdx.x * 256 + threadIdx.x;
  if (i >= n8) return;
  const float4v a = *(const float4v*)(in + (size_t)i * 8);
  const float4v b = *(const float4v*)(in + (size_t)i * 8 + 4);
  ushort8 o;
  o[0] = f2h(a[0]); o[1] = f2h(a[1]); o[2] = f2h(a[2]); o[3] = f2h(a[3]);
  o[4] = f2h(b[0]); o[5] = f2h(b[1]); o[6] = f2h(b[2]); o[7] = f2h(b[3]);
  *(ushort8*)(out + (size_t)i * 8) = o;
}

extern "C" void kernel_launch(void* const* d_in, const int* in_sizes, int n_in,
                              void* d_out, int out_size, void* d_ws, size_t ws_size,
                              hipStream_t stream) {
  (void)in_sizes; (void)n_in; (void)out_size;
  const float* x  = (const float*)d_in[0];
  const float* Wq = (const float*)d_in[1];
  const float* bq = (const float*)d_in[2];
  const float* Wk = (const float*)d_in[3];
  const float* bk = (const float*)d_in[4];
  const float* Wv = (const float*)d_in[5];
  const float* bv = (const float*)d_in[6];
  float* out = (float*)d_out;

  char* ws = (char*)d_ws;
  size_t off = 0;
  auto alloc = [&](size_t bytes) -> char* {
    char* p = ws + off;
    off += (bytes + 255) & ~(size_t)255;
    return p;
  };
  const size_t MS = (size_t)B_ * S_;  // 16384 rows total
  u16* xh = (u16*)alloc(MS * D_ * 2);
  u16* Wh = (u16*)alloc(3ull * D_ * D_ * 2);
  u16* Qb = (u16*)alloc(MS * D_ * 2);
  u16* Kb = (u16*)alloc(MS * D_ * 2);
  u16* Vt = (u16*)alloc(MS * D_ * 2);
  const size_t Efull = (size_t)B_ * S_ * S_ * 2;
  const bool full = ws_size >= off + Efull;  // ~136 MB total; else per-batch E (~77 MB)
  u16* E = (u16*)alloc(full ? Efull : (size_t)S_ * S_ * 2);

  // fp32 -> fp16 converts
  {
    const int n8 = (int)(MS * D_ / 8);
    cvt_kernel<<<dim3((n8 + 255) / 256), dim3(256), 0, stream>>>(x, xh, n8);
    const int w8 = D_ * D_ / 8;
    cvt_kernel<<<dim3((w8 + 255) / 256), dim3(256), 0, stream>>>(Wq, Wh, w8);
    cvt_kernel<<<dim3((w8 + 255) / 256), dim3(256), 0, stream>>>(Wk, Wh + D_ * D_, w8);
    cvt_kernel<<<dim3((w8 + 255) / 256), dim3(256), 0, stream>>>(Wv, Wh + 2 * D_ * D_, w8);
  }

  // Q/K/V projections (z = 0/1/2)
  proj_kernel<<<dim3(D_ / 128, MS / 128, 3), dim3(256), 0, stream>>>(
      xh, Wh, bq, bk, bv, Qb, Kb, Vt);

  if (full) {
    qk_kernel<<<dim3(S_ / 128, S_ / 128, B_), dim3(256), 0, stream>>>(
        Qb, Kb, E, (size_t)S_ * D_, (size_t)S_ * S_);
    softmax_kernel<<<dim3(B_ * S_ / 4), dim3(256), 0, stream>>>(E);
    pv_kernel<<<dim3(D_ / 128, S_ / 128, B_), dim3(256), 0, stream>>>(
        E, Vt, out, (size_t)S_ * S_, (size_t)D_ * S_, (size_t)S_ * D_);
  } else {
    for (int b = 0; b < B_; ++b) {
      qk_kernel<<<dim3(S_ / 128, S_ / 128, 1), dim3(256), 0, stream>>>(
          Qb + (size_t)b * S_ * D_, Kb + (size_t)b * S_ * D_, E, 0, 0);
      softmax_kernel<<<dim3(S_ / 4), dim3(256), 0, stream>>>(E);
      pv_kernel<<<dim3(D_ / 128, S_ / 128, 1), dim3(256), 0, stream>>>(
          E, Vt + (size_t)b * D_ * S_, out + (size_t)b * S_ * D_, 0, 0, 0);
    }
  }
}

// Round 5
// 160.624 us; speedup vs baseline: 1.2468x; 1.0589x over previous
//
#include <hip/hip_runtime.h>

typedef unsigned short u16;
typedef _Float16 f16;

using half8   = __attribute__((ext_vector_type(8))) _Float16;
using f32x4   = __attribute__((ext_vector_type(4))) float;
using ushort8 = __attribute__((ext_vector_type(8))) unsigned short;
using us4     = __attribute__((ext_vector_type(4))) unsigned short;
using float4v = __attribute__((ext_vector_type(4))) float;

#define B_  8
#define S_  2048
#define D_  512
#define BK  32
#define TILE_ELEMS 4096   // 128 rows x 32 cols (u16) = 8KB per matrix per buffer
#define BUF_ELEMS  8192   // A tile + B tile

__device__ __forceinline__ u16 f2h(float f) {
  f16 h = (f16)f;
  u16 u;
  __builtin_memcpy(&u, &h, 2);
  return u;
}

__device__ __forceinline__ float h2f(u16 h) {
  f16 x;
  __builtin_memcpy(&x, &h, 2);
  return (float)x;
}

__device__ __forceinline__ void stage16(const void* g, void* l) {
  __builtin_amdgcn_global_load_lds((const __attribute__((address_space(1))) void*)g,
                                   (__attribute__((address_space(3))) void*)l,
                                   16, 0, 0);
}

// XCD-aware bijective remap (all grids have nwg % 8 == 0).
__device__ __forceinline__ void xcd_remap(int& bx, int& by, int& bz) {
  const int lin = ((int)blockIdx.z * (int)gridDim.y + (int)blockIdx.y) * (int)gridDim.x
                  + (int)blockIdx.x;
  const int nwg = (int)gridDim.x * (int)gridDim.y * (int)gridDim.z;
  const int swz = (lin & 7) * (nwg >> 3) + (lin >> 3);
  bx = swz % (int)gridDim.x;
  const int tmp = swz / (int)gridDim.x;
  by = tmp % (int)gridDim.y;
  bz = tmp / (int)gridDim.y;
}

// C[M x N] = A[M x K] * B[N x K]^T, fp16 in, fp32 accum. 128x128 tile, BK=32.
// 4 LDS buffers, depth-3 prefetch, counted vmcnt (never drained mid-loop),
// one raw s_barrier per iter (wait-own-vmcnt BEFORE barrier covers cross-wave
// staging portions; buf[(t+3)&3] == buf[(t-1)&3] is reusable once all waves
// passed barrier t).
// LDS tile layout (per matrix): paired rows — [64 LDS-rows of 128B][8 slots
// of 16B]; global (row r, k-chunk g[0..3]) -> LDS row r>>1, slot
// (((r&1)<<2)|g) ^ ((r>>1)&7). Bijective; fragment reads <=2-way bank alias
// (free); gload_lds dest stays linear, global source is pre-swizzled.
// mfma_f32_16x16x32_f16 frags: A/B row|col = lane&15, k = (lane>>4)*8 + j;
//                              C/D col = lane&15, row = (lane>>4)*4 + reg.
__device__ __forceinline__ void gemm_core(const u16* __restrict__ A, const u16* __restrict__ B,
                                          int K, int m0, int n0,
                                          u16* lds, f32x4 acc[4][4]) {
  const int tid  = threadIdx.x;
  const int lane = tid & 63;
  const int wave = tid >> 6;
  const int wr = wave >> 1, wc = wave & 1;
  const int fr   = lane & 15;
  const int fgrp = lane >> 4;  // k-chunk 0..3

  // staging source coords: sweep s covers bytes p = tid*16 + s*4096 of the tile image
  int sr[2], sc[2];
  #pragma unroll
  for (int s = 0; s < 2; ++s) {
    const int p    = tid * 16 + s * 4096;
    const int R    = p >> 7;
    const int slot = (p >> 4) & 7;
    const int s0   = slot ^ (R & 7);
    sr[s] = 2 * R + (s0 >> 2);
    sc[s] = (s0 & 3) * 8;
  }

  // fragment read byte-offsets within a tile image
  int offA[4], offB[4];
  #pragma unroll
  for (int m = 0; m < 4; ++m) {
    const int ra = wr * 64 + m * 16 + fr;
    const int Ra = ra >> 1;
    offA[m] = Ra * 128 + (((((ra & 1) << 2) | fgrp) ^ (Ra & 7)) << 4);
    const int rb = wc * 64 + m * 16 + fr;
    const int Rb = rb >> 1;
    offB[m] = Rb * 128 + (((((rb & 1) << 2) | fgrp) ^ (Rb & 7)) << 4);
  }

  const f32x4 vzero = {0.f, 0.f, 0.f, 0.f};
  #pragma unroll
  for (int m = 0; m < 4; ++m)
    #pragma unroll
    for (int n = 0; n < 4; ++n)
      acc[m][n] = vzero;

  const int T = K / BK;

  auto STAGE = [&](int t, u16* buf) {
    #pragma unroll
    for (int s = 0; s < 2; ++s) {
      stage16(A + (size_t)(m0 + sr[s]) * K + t * BK + sc[s],
              buf + s * 2048 + wave * 512);
      stage16(B + (size_t)(n0 + sr[s]) * K + t * BK + sc[s],
              buf + TILE_ELEMS + s * 2048 + wave * 512);
    }
  };

  // prologue: tiles 0,1,2 in flight (12 loads/wave)
  STAGE(0, lds);
  STAGE(1, lds + BUF_ELEMS);
  STAGE(2, lds + 2 * BUF_ELEMS);

  int t = 0;
#define GEMM_ITER(WN)                                                            \
  {                                                                              \
    asm volatile("s_waitcnt vmcnt(" #WN ")\n\ts_barrier" ::: "memory");          \
    const u16* buf = lds + (t & 3) * BUF_ELEMS;                                  \
    half8 a[4], b[4];                                                            \
    _Pragma("unroll")                                                            \
    for (int m = 0; m < 4; ++m)                                                  \
      a[m] = *(const half8*)((const char*)buf + offA[m]);                        \
    _Pragma("unroll")                                                            \
    for (int n = 0; n < 4; ++n)                                                  \
      b[n] = *(const half8*)((const char*)(buf + TILE_ELEMS) + offB[n]);         \
    if (t + 3 < T) STAGE(t + 3, lds + ((t + 3) & 3) * BUF_ELEMS);                \
    __builtin_amdgcn_s_setprio(1);                                               \
    _Pragma("unroll")                                                            \
    for (int m = 0; m < 4; ++m)                                                  \
      _Pragma("unroll")                                                          \
      for (int n = 0; n < 4; ++n)                                                \
        acc[m][n] = __builtin_amdgcn_mfma_f32_16x16x32_f16(a[m], b[n],           \
                                                           acc[m][n], 0, 0, 0); \
    __builtin_amdgcn_s_setprio(0);                                               \
  }

  for (; t < T - 2; ++t) GEMM_ITER(8)
  GEMM_ITER(4); ++t;
  GEMM_ITER(0);
#undef GEMM_ITER
}

// ---------------- projections: Q/K normal fp16 store, V transposed [b][d][s] ----------------
__global__ __launch_bounds__(256) void proj_kernel(
    const u16* __restrict__ xh, const u16* __restrict__ Wh,
    const float* __restrict__ bq, const float* __restrict__ bk, const float* __restrict__ bv,
    u16* __restrict__ Qb, u16* __restrict__ Kb, u16* __restrict__ Vt) {
  __shared__ __align__(16) u16 lds[4 * BUF_ELEMS];
  int bx, by, bz;
  xcd_remap(bx, by, bz);
  const int z  = bz;
  const int m0 = by * 128;
  const int n0 = bx * 128;
  const u16* W = Wh + (size_t)z * D_ * D_;
  const float* bias = (z == 0) ? bq : (z == 1) ? bk : bv;
  f32x4 acc[4][4];
  gemm_core(xh, W, D_, m0, n0, lds, acc);

  const int lane = threadIdx.x & 63;
  const int wave = threadIdx.x >> 6;
  const int wr = wave >> 1, wc = wave & 1;
  #pragma unroll
  for (int m = 0; m < 4; ++m) {
    const int gr0 = m0 + wr * 64 + m * 16 + ((lane >> 4) << 2);
    #pragma unroll
    for (int n = 0; n < 4; ++n) {
      const int gc = n0 + wc * 64 + n * 16 + (lane & 15);
      const float bb = bias[gc];
      if (z < 2) {
        u16* O = z ? Kb : Qb;
        #pragma unroll
        for (int r = 0; r < 4; ++r)
          O[(size_t)(gr0 + r) * D_ + gc] = f2h(acc[m][n][r] + bb);
      } else {
        const int bidx = gr0 >> 11;      // 2048 rows per batch; tiles never straddle
        const int s    = gr0 & 2047;
        us4 p;
        #pragma unroll
        for (int r = 0; r < 4; ++r) p[r] = f2h(acc[m][n][r] + bb);
        *(us4*)(Vt + ((size_t)bidx * D_ + gc) * S_ + s) = p;
      }
    }
  }
}

// ---------------- QK^T -> E fp16 ----------------
__global__ __launch_bounds__(256) void qk_kernel(
    const u16* __restrict__ Qb, const u16* __restrict__ Kb, u16* __restrict__ E,
    size_t sA, size_t sE) {
  __shared__ __align__(16) u16 lds[4 * BUF_ELEMS];
  int bx, by, bz;
  xcd_remap(bx, by, bz);
  const int z  = bz;
  const int m0 = by * 128;
  const int n0 = bx * 128;
  f32x4 acc[4][4];
  gemm_core(Qb + (size_t)z * sA, Kb + (size_t)z * sA, D_, m0, n0, lds, acc);

  u16* Eb = E + (size_t)z * sE;
  const int lane = threadIdx.x & 63;
  const int wave = threadIdx.x >> 6;
  const int wr = wave >> 1, wc = wave & 1;
  #pragma unroll
  for (int m = 0; m < 4; ++m) {
    const int gr0 = m0 + wr * 64 + m * 16 + ((lane >> 4) << 2);
    #pragma unroll
    for (int n = 0; n < 4; ++n) {
      const int gc = n0 + wc * 64 + n * 16 + (lane & 15);
      #pragma unroll
      for (int r = 0; r < 4; ++r)
        Eb[(size_t)(gr0 + r) * S_ + gc] = f2h(acc[m][n][r]);
    }
  }
}

// ---------------- row softmax, in place fp16 -> fp16 ----------------
__global__ __launch_bounds__(256) void softmax_kernel(u16* __restrict__ E) {
  const int row  = blockIdx.x * 4 + (threadIdx.x >> 6);
  const int lane = threadIdx.x & 63;
  u16* R = E + (size_t)row * S_;
  float e[32];
  #pragma unroll
  for (int i = 0; i < 4; ++i) {
    ushort8 v = *(const ushort8*)(R + i * 512 + lane * 8);
    #pragma unroll
    for (int j = 0; j < 8; ++j) e[i * 8 + j] = h2f(v[j]);
  }
  float m = e[0];
  #pragma unroll
  for (int i = 1; i < 32; ++i) m = fmaxf(m, e[i]);
  for (int off = 32; off > 0; off >>= 1) m = fmaxf(m, __shfl_xor(m, off, 64));
  float s = 0.f;
  #pragma unroll
  for (int i = 0; i < 32; ++i) { e[i] = __expf(e[i] - m); s += e[i]; }
  for (int off = 32; off > 0; off >>= 1) s += __shfl_xor(s, off, 64);
  const float inv = 1.f / s;
  #pragma unroll
  for (int i = 0; i < 4; ++i) {
    ushort8 v;
    #pragma unroll
    for (int j = 0; j < 8; ++j) v[j] = f2h(e[i * 8 + j] * inv);
    *(ushort8*)(R + i * 512 + lane * 8) = v;
  }
}

// ---------------- PV -> fp32 out ----------------
__global__ __launch_bounds__(256) void pv_kernel(
    const u16* __restrict__ P, const u16* __restrict__ Vt, float* __restrict__ out,
    size_t sP, size_t sV, size_t sO) {
  __shared__ __align__(16) u16 lds[4 * BUF_ELEMS];
  int bx, by, bz;
  xcd_remap(bx, by, bz);
  const int z  = bz;
  const int m0 = by * 128;
  const int n0 = bx * 128;
  f32x4 acc[4][4];
  gemm_core(P + (size_t)z * sP, Vt + (size_t)z * sV, S_, m0, n0, lds, acc);

  float* Ob = out + (size_t)z * sO;
  const int lane = threadIdx.x & 63;
  const int wave = threadIdx.x >> 6;
  const int wr = wave >> 1, wc = wave & 1;
  #pragma unroll
  for (int m = 0; m < 4; ++m) {
    const int gr0 = m0 + wr * 64 + m * 16 + ((lane >> 4) << 2);
    #pragma unroll
    for (int n = 0; n < 4; ++n) {
      const int gc = n0 + wc * 64 + n * 16 + (lane & 15);
      #pragma unroll
      for (int r = 0; r < 4; ++r)
        Ob[(size_t)(gr0 + r) * D_ + gc] = acc[m][n][r];
    }
  }
}

// ---------------- fp32 -> fp16 converts ----------------
__global__ __launch_bounds__(256) void cvt_kernel(const float* __restrict__ in,
                                                  u16* __restrict__ out, int n8) {
  const int i = blockIdx.x * 256 + threadIdx.x;
  if (i >= n8) return;
  const float4v a = *(const float4v*)(in + (size_t)i * 8);
  const float4v b = *(const float4v*)(in + (size_t)i * 8 + 4);
  ushort8 o;
  o[0] = f2h(a[0]); o[1] = f2h(a[1]); o[2] = f2h(a[2]); o[3] = f2h(a[3]);
  o[4] = f2h(b[0]); o[5] = f2h(b[1]); o[6] = f2h(b[2]); o[7] = f2h(b[3]);
  *(ushort8*)(out + (size_t)i * 8) = o;
}

__global__ __launch_bounds__(256) void cvt3_kernel(const float* __restrict__ w0,
                                                   const float* __restrict__ w1,
                                                   const float* __restrict__ w2,
                                                   u16* __restrict__ out, int n8) {
  const int i = blockIdx.x * 256 + threadIdx.x;
  if (i >= n8) return;
  const float* in = (blockIdx.y == 0) ? w0 : (blockIdx.y == 1) ? w1 : w2;
  u16* o_ = out + (size_t)blockIdx.y * D_ * D_;
  const float4v a = *(const float4v*)(in + (size_t)i * 8);
  const float4v b = *(const float4v*)(in + (size_t)i * 8 + 4);
  ushort8 o;
  o[0] = f2h(a[0]); o[1] = f2h(a[1]); o[2] = f2h(a[2]); o[3] = f2h(a[3]);
  o[4] = f2h(b[0]); o[5] = f2h(b[1]); o[6] = f2h(b[2]); o[7] = f2h(b[3]);
  *(ushort8*)(o_ + (size_t)i * 8) = o;
}

extern "C" void kernel_launch(void* const* d_in, const int* in_sizes, int n_in,
                              void* d_out, int out_size, void* d_ws, size_t ws_size,
                              hipStream_t stream) {
  (void)in_sizes; (void)n_in; (void)out_size;
  const float* x  = (const float*)d_in[0];
  const float* Wq = (const float*)d_in[1];
  const float* bq = (const float*)d_in[2];
  const float* Wk = (const float*)d_in[3];
  const float* bk = (const float*)d_in[4];
  const float* Wv = (const float*)d_in[5];
  const float* bv = (const float*)d_in[6];
  float* out = (float*)d_out;

  char* ws = (char*)d_ws;
  size_t off = 0;
  auto alloc = [&](size_t bytes) -> char* {
    char* p = ws + off;
    off += (bytes + 255) & ~(size_t)255;
    return p;
  };
  const size_t MS = (size_t)B_ * S_;  // 16384 rows total
  u16* xh = (u16*)alloc(MS * D_ * 2);
  u16* Wh = (u16*)alloc(3ull * D_ * D_ * 2);
  u16* Qb = (u16*)alloc(MS * D_ * 2);
  u16* Kb = (u16*)alloc(MS * D_ * 2);
  u16* Vt = (u16*)alloc(MS * D_ * 2);
  const size_t Efull = (size_t)B_ * S_ * S_ * 2;
  const bool full = ws_size >= off + Efull;  // ~136 MB total; else per-batch E
  u16* E = (u16*)alloc(full ? Efull : (size_t)S_ * S_ * 2);

  // fp32 -> fp16 converts
  {
    const int n8 = (int)(MS * D_ / 8);
    cvt_kernel<<<dim3((n8 + 255) / 256), dim3(256), 0, stream>>>(x, xh, n8);
    const int w8 = D_ * D_ / 8;
    cvt3_kernel<<<dim3((w8 + 255) / 256, 3), dim3(256), 0, stream>>>(Wq, Wk, Wv, Wh, w8);
  }

  // Q/K/V projections (z = 0/1/2)
  proj_kernel<<<dim3(D_ / 128, MS / 128, 3), dim3(256), 0, stream>>>(
      xh, Wh, bq, bk, bv, Qb, Kb, Vt);

  if (full) {
    qk_kernel<<<dim3(S_ / 128, S_ / 128, B_), dim3(256), 0, stream>>>(
        Qb, Kb, E, (size_t)S_ * D_, (size_t)S_ * S_);
    softmax_kernel<<<dim3(B_ * S_ / 4), dim3(256), 0, stream>>>(E);
    pv_kernel<<<dim3(D_ / 128, S_ / 128, B_), dim3(256), 0, stream>>>(
        E, Vt, out, (size_t)S_ * S_, (size_t)D_ * S_, (size_t)S_ * D_);
  } else {
    for (int b = 0; b < B_; ++b) {
      qk_kernel<<<dim3(S_ / 128, S_ / 128, 1), dim3(256), 0, stream>>>(
          Qb + (size_t)b * S_ * D_, Kb + (size_t)b * S_ * D_, E, 0, 0);
      softmax_kernel<<<dim3(S_ / 4), dim3(256), 0, stream>>>(E);
      pv_kernel<<<dim3(D_ / 128, S_ / 128, 1), dim3(256), 0, stream>>>(
          E, Vt + (size_t)b * D_ * S_, out + (size_t)b * S_ * D_, 0, 0, 0);
    }
  }
}